// Round 19
// baseline (200.765 us; speedup 1.0000x reference)
//
#include <hip/hip_runtime.h>

typedef __attribute__((ext_vector_type(8))) short short8;
typedef __attribute__((ext_vector_type(8))) unsigned short ushort8;
typedef __attribute__((ext_vector_type(4))) float f32x4;
typedef unsigned short ushort_t;

__device__ __forceinline__ ushort_t f2bf(float f) {
    unsigned u = __builtin_bit_cast(unsigned, f);
    u += 0x7fffu + ((u >> 16) & 1u);
    return (ushort_t)(u >> 16);
}

__device__ __forceinline__ void load_lds16b(const void* gp, void* lp) {
    __builtin_amdgcn_global_load_lds(
        (const __attribute__((address_space(1))) void*)gp,
        (__attribute__((address_space(3))) void*)lp, 16, 0, 0);
}

// ---------------------------------------------------------------------------
// prep kernel = pool + weight prep. launch_bounds (256,2): allows ~128 VGPR
// so the pool's 16-deep f32x4 batch is actually live (loads in flight);
// streaming sections use few VGPRs so their residency is unaffected.
//  [0,480)       pool: block = (bt,c), waves sweep rows w+4j, batch-16 loads
//  [480,6240)    cvt f32->bf16: w_qkv, w_tf, w_red
//  [6240,6816)   transpose+cvt w_tp -> WTT
//  [6816,7104)   transpose+cvt conv_w -> WCVT
//  [7104,7144)   cls rows -> GA
//  [7144,7240)   BC[i]  = w_tf[i,:].b_tp + b_tf[i]
//  [7240,7336)   BC2[j] = w_red[j,:].conv_b + b_red[j]
// ---------------------------------------------------------------------------
__global__ __launch_bounds__(256, 2) void prep_kernel(
    const float* __restrict__ x, const float* __restrict__ w_qkv,
    const float* __restrict__ w_tf, const float* __restrict__ w_red,
    const float* __restrict__ conv_w, const float* __restrict__ w_tp,
    const float* __restrict__ b_tp, const float* __restrict__ b_tf,
    const float* __restrict__ conv_b, const float* __restrict__ b_red,
    const float* __restrict__ cls,
    ushort_t* __restrict__ AP, ushort_t* __restrict__ WQ,
    ushort_t* __restrict__ WF, ushort_t* __restrict__ WR,
    ushort_t* __restrict__ WCVT, ushort_t* __restrict__ WTT,
    float* __restrict__ BC, float* __restrict__ BC2,
    float* __restrict__ GA) {
    __shared__ __align__(16) float smem[64 * 68];
    int blk = blockIdx.x, tid = threadIdx.x;
    if (blk < 480) {
        int bt = blk / 3, c = blk % 3;
        int b = bt / 20, t = bt % 20;
        int w = tid >> 6, lane = tid & 63;
        int cl = lane < 56 ? lane : 55;      // clamp; garbage zeroed pre-reduce
        const float* base = x + (size_t)((b * 3 + c) * 20 + t) * 50176
                              + (size_t)w * 224 + 4 * cl;
        f32x4 acc4[4];
        #pragma unroll
        for (int q = 0; q < 4; ++q) acc4[q] = (f32x4){0.f, 0.f, 0.f, 0.f};
        #pragma unroll
        for (int b16 = 0; b16 < 4; ++b16) {
            const int cnt = (b16 == 3) ? 8 : 16;
            f32x4 v[16];
            #pragma unroll
            for (int u = 0; u < 16; ++u) {
                if (u < cnt) {
                    int j = b16 * 16 + u;
                    v[u] = *(const f32x4*)(base + (size_t)j * 896);
                }
            }
            #pragma unroll
            for (int u = 0; u < 16; ++u)
                if (u < cnt) acc4[u & 3] += v[u];
        }
        // zero clamped lanes BEFORE cross-lane reduce (they'd pollute sums)
        if (lane >= 56) {
            #pragma unroll
            for (int q = 0; q < 4; ++q) acc4[q] = (f32x4){0.f, 0.f, 0.f, 0.f};
        }
        #pragma unroll
        for (int q = 0; q < 4; ++q) {
            #pragma unroll
            for (int m = 4; m <= 32; m <<= 1) {
                acc4[q][0] += __shfl_xor(acc4[q][0], m);
                acc4[q][1] += __shfl_xor(acc4[q][1], m);
                acc4[q][2] += __shfl_xor(acc4[q][2], m);
                acc4[q][3] += __shfl_xor(acc4[q][3], m);
            }
        }
        if (lane < 4) {
            #pragma unroll
            for (int q = 0; q < 4; ++q) {
                int i = w + 4 * q;
                ushort4 o;
                o.x = f2bf(acc4[q][0] * (1.f / 196.f));
                o.y = f2bf(acc4[q][1] * (1.f / 196.f));
                o.z = f2bf(acc4[q][2] * (1.f / 196.f));
                o.w = f2bf(acc4[q][3] * (1.f / 196.f));
                *(ushort4*)(AP + (size_t)bt * 768 + c * 256 + i * 16 + 4 * lane) = o;
            }
        }
    } else if (blk < 6240) {
        long c = (long)(blk - 480) * 256 + tid;
        const float* s; ushort_t* d; long i;
        if (c < 884736)       { s = w_qkv; d = WQ; i = c; }
        else if (c < 1179648) { s = w_tf;  d = WF; i = c - 884736; }
        else                  { s = w_red; d = WR; i = c - 1179648; }
        i <<= 3;
        f32x4 a = *(const f32x4*)(s + i);
        f32x4 b = *(const f32x4*)(s + i + 4);
        ushort8 o;
        o[0] = f2bf(a[0]); o[1] = f2bf(a[1]); o[2] = f2bf(a[2]); o[3] = f2bf(a[3]);
        o[4] = f2bf(b[0]); o[5] = f2bf(b[1]); o[6] = f2bf(b[2]); o[7] = f2bf(b[3]);
        *(ushort8*)(d + i) = o;
    } else if (blk < 6816) {
        int tb = blk - 6240;
        int bi = tb / 24, bj = tb % 24;
        int r0 = (tid >> 4) << 2;
        int c0 = (tid & 15) << 2;
        #pragma unroll
        for (int rr = 0; rr < 4; ++rr) {
            f32x4 v = *(const f32x4*)(w_tp + (size_t)(bi * 64 + r0 + rr) * 1536 + bj * 64 + c0);
            smem[(r0 + rr) * 68 + c0 + 0] = v[0];
            smem[(r0 + rr) * 68 + c0 + 1] = v[1];
            smem[(r0 + rr) * 68 + c0 + 2] = v[2];
            smem[(r0 + rr) * 68 + c0 + 3] = v[3];
        }
        __syncthreads();
        #pragma unroll
        for (int rr = 0; rr < 4; ++rr) {
            int jj = r0 + rr;
            ushort4 o;
            o.x = f2bf(smem[(c0 + 0) * 68 + jj]);
            o.y = f2bf(smem[(c0 + 1) * 68 + jj]);
            o.z = f2bf(smem[(c0 + 2) * 68 + jj]);
            o.w = f2bf(smem[(c0 + 3) * 68 + jj]);
            *(ushort4*)(WTT + (size_t)(bj * 64 + jj) * 1536 + bi * 64 + c0) = o;
        }
    } else if (blk < 7104) {
        int tb = blk - 6816;
        int bi = tb / 12, bj = tb % 12;
        int r0 = (tid >> 4) << 2;
        int c0 = (tid & 15) << 2;
        #pragma unroll
        for (int rr = 0; rr < 4; ++rr) {
            f32x4 v = *(const f32x4*)(conv_w + (size_t)(bi * 64 + r0 + rr) * 768 + bj * 64 + c0);
            smem[(r0 + rr) * 68 + c0 + 0] = v[0];
            smem[(r0 + rr) * 68 + c0 + 1] = v[1];
            smem[(r0 + rr) * 68 + c0 + 2] = v[2];
            smem[(r0 + rr) * 68 + c0 + 3] = v[3];
        }
        __syncthreads();
        #pragma unroll
        for (int rr = 0; rr < 4; ++rr) {
            int jj = r0 + rr;
            ushort4 o;
            o.x = f2bf(smem[(c0 + 0) * 68 + jj]);
            o.y = f2bf(smem[(c0 + 1) * 68 + jj]);
            o.z = f2bf(smem[(c0 + 2) * 68 + jj]);
            o.w = f2bf(smem[(c0 + 3) * 68 + jj]);
            *(ushort4*)(WCVT + (size_t)(bj * 64 + jj) * 1536 + bi * 64 + c0) = o;
        }
    } else if (blk < 7144) {
        int cblk = blk - 7104;
        int b = cblk / 5, n = cblk % 5;
        size_t row = (size_t)(b * 25 + n * 5) * 1536;
        #pragma unroll
        for (int j = 0; j < 6; ++j) {
            int d = tid + j * 256;
            GA[row + d] = cls[n * 1536 + d];
        }
    } else if (blk < 7240) {
        int bb = blk - 7144;
        int row = bb * 16 + (tid >> 4);
        int sub = tid & 15;
        float acc = 0.f;
        for (int j = 0; j < 96; ++j) {
            int k = sub + j * 16;
            acc += w_tf[(size_t)row * 1536 + k] * b_tp[k];
        }
        acc += __shfl_xor(acc, 1); acc += __shfl_xor(acc, 2);
        acc += __shfl_xor(acc, 4); acc += __shfl_xor(acc, 8);
        if (sub == 0) BC[row] = acc + b_tf[row];
    } else {
        int bb = blk - 7240;
        int row = bb * 16 + (tid >> 4);
        int sub = tid & 15;
        float acc = 0.f;
        for (int j = 0; j < 48; ++j) {
            int n0 = sub + j * 16;
            acc += w_red[(size_t)row * 1536 + n0] * conv_b[n0];
            acc += w_red[(size_t)row * 1536 + n0 + 768] * conv_b[n0 + 768];
        }
        acc += __shfl_xor(acc, 1); acc += __shfl_xor(acc, 2);
        acc += __shfl_xor(acc, 4); acc += __shfl_xor(acc, 8);
        if (sub == 0) BC2[row] = acc + b_red[row];
    }
}

// ---------------------------------------------------------------------------
// 128x128-tile 4-wave GEMM tile (r16, verified)
// ---------------------------------------------------------------------------
template <bool OUT_BF16>
__device__ __forceinline__ void gemm128_tile(
    char* lds, const ushort_t* __restrict__ A, const ushort_t* __restrict__ B,
    void* __restrict__ Cv, int M, int N, int K, int KS, int tn, int tm) {
    const int tid = threadIdx.x;
    const int lane = tid & 63;
    const int w = tid >> 6;
    const int wr = w >> 1, wc = w & 1;

    f32x4 acc[4][4];
    #pragma unroll
    for (int m = 0; m < 4; ++m)
        #pragma unroll
        for (int n = 0; n < 4; ++n)
            acc[m][n] = (f32x4){0.f, 0.f, 0.f, 0.f};

    const int nK = K >> 6;
    const int rbase = lane >> 3, cc = lane & 7;

    auto stage = [&](int k0, int buf) {
        char* lA = lds + buf * 32768;
        char* lB = lA + 16384;
        #pragma unroll
        for (int j = 0; j < 4; ++j) {
            int row = w * 32 + j * 8 + rbase;
            int cf = cc ^ (row & 7);
            int ga = tm * 128 + row; if (ga > M - 1) ga = M - 1;
            load_lds16b(A + (size_t)ga * KS + (k0 + cf * 8),
                        lA + (w * 32 + j * 8) * 128);
        }
        #pragma unroll
        for (int j = 0; j < 4; ++j) {
            int row = w * 32 + j * 8 + rbase;
            int cf = cc ^ (row & 7);
            load_lds16b(B + (size_t)(tn * 128 + row) * KS + (k0 + cf * 8),
                        lB + (w * 32 + j * 8) * 128);
        }
    };

    stage(0, 0);
    asm volatile("s_waitcnt vmcnt(0)" ::: "memory");
    __builtin_amdgcn_s_barrier();
    __builtin_amdgcn_sched_barrier(0);
    for (int t = 0; t < nK; ++t) {
        int cur = t & 1;
        if (t + 1 < nK) stage((t + 1) << 6, cur ^ 1);
        __builtin_amdgcn_sched_barrier(0);
        const char* lA = lds + cur * 32768;
        const char* lB = lA + 16384;
        #pragma unroll
        for (int ks = 0; ks < 2; ++ks) {
            short8 av[4], bv[4];
            const int rlo = lane & 15;
            const int chi = ks * 4 + (lane >> 4);
            #pragma unroll
            for (int m = 0; m < 4; ++m) {
                int r = wr * 64 + m * 16 + rlo;
                av[m] = *(const short8*)(lA + r * 128 + ((chi ^ (r & 7)) << 4));
            }
            #pragma unroll
            for (int n = 0; n < 4; ++n) {
                int r = wc * 64 + n * 16 + rlo;
                bv[n] = *(const short8*)(lB + r * 128 + ((chi ^ (r & 7)) << 4));
            }
            #pragma unroll
            for (int m = 0; m < 4; ++m)
                #pragma unroll
                for (int n = 0; n < 4; ++n)
                    acc[m][n] = __builtin_amdgcn_mfma_f32_16x16x32_bf16(
                        av[m], bv[n], acc[m][n], 0, 0, 0);
        }
        asm volatile("s_waitcnt vmcnt(0)" ::: "memory");
        __builtin_amdgcn_s_barrier();
        __builtin_amdgcn_sched_barrier(0);
    }

    const int c_l = lane & 15, r_q = (lane >> 4) * 4;
    #pragma unroll
    for (int m = 0; m < 4; ++m) {
        #pragma unroll
        for (int reg = 0; reg < 4; ++reg) {
            int r_ = tm * 128 + wr * 64 + m * 16 + r_q + reg;
            if (r_ < M) {
                #pragma unroll
                for (int n = 0; n < 4; ++n) {
                    int cc_ = tn * 128 + wc * 64 + n * 16 + c_l;
                    float v = acc[m][n][reg];
                    if (OUT_BF16) ((ushort_t*)Cv)[(size_t)r_ * N + cc_] = f2bf(v);
                    else          ((float*)Cv)[(size_t)r_ * N + cc_] = v;
                }
            }
        }
    }
}

// Wc (144 tiles) + WRC (72 tiles), one 128-tile launch
__global__ __launch_bounds__(256) void wcf_kernel(
    const ushort_t* __restrict__ WF, const ushort_t* __restrict__ WTT,
    const ushort_t* __restrict__ WR, const ushort_t* __restrict__ WCVT,
    ushort_t* __restrict__ WC, ushort_t* __restrict__ WRC) {
    __shared__ __align__(16) char lds[65536];
    int task = blockIdx.x;
    if (task < 144)
        gemm128_tile<true>(lds, WF, WTT, WC, 1536, 1536, 1536, 1536,
                           task % 12, task / 12);
    else {
        int t2 = task - 144;
        gemm128_tile<true>(lds, WR, WCVT, WRC, 1536, 768, 1536, 1536,
                           t2 % 6, t2 / 6);
    }
}

// ---------------------------------------------------------------------------
// single-wave GEMM tile (round-13, unchanged)
// ---------------------------------------------------------------------------
template <int MT, bool OUT_BF16, bool HAS_BIAS, bool HAS_RES, bool CLS_SWAP, bool BUILD_G>
__device__ __forceinline__ void gemm_tile(
    char* lds, int lane, int tn, int tm,
    const ushort_t* __restrict__ A, const ushort_t* __restrict__ B,
    void* __restrict__ Cv, const float* __restrict__ bias,
    const float* __restrict__ res, int M, int N, int K, int KS,
    float* __restrict__ g_out, const float* __restrict__ temb,
    const float* __restrict__ ts, const float* __restrict__ w_num,
    const float* __restrict__ b_num) {
    constexpr int BUFB = MT * 2048 + 8192;

    f32x4 acc[MT][4];
    #pragma unroll
    for (int m = 0; m < MT; ++m)
        #pragma unroll
        for (int n = 0; n < 4; ++n)
            acc[m][n] = (f32x4){0.f, 0.f, 0.f, 0.f};

    const int nK = K >> 6;
    const int rbase = lane >> 3, cc = lane & 7;

    auto stage = [&](int k0, int buf) {
        char* lA = lds + buf * BUFB;
        char* lB = lA + MT * 2048;
        #pragma unroll
        for (int j = 0; j < MT * 2; ++j) {
            int row = j * 8 + rbase;
            int cf = cc ^ (row & 7);
            int ga = tm * (MT * 16) + row; if (ga > M - 1) ga = M - 1;
            load_lds16b(A + (size_t)ga * KS + (k0 + cf * 8), lA + j * 1024);
        }
        #pragma unroll
        for (int j = 0; j < 8; ++j) {
            int row = j * 8 + rbase;
            int cf = cc ^ (row & 7);
            load_lds16b(B + (size_t)(tn * 64 + row) * KS + (k0 + cf * 8), lB + j * 1024);
        }
    };

    stage(0, 0);
    for (int t = 0; t < nK; ++t) {
        int cur = t & 1;
        if (t + 1 < nK) {
            stage((t + 1) << 6, cur ^ 1);
            if constexpr (MT == 2) asm volatile("s_waitcnt vmcnt(12)" ::: "memory");
            else                   asm volatile("s_waitcnt vmcnt(16)" ::: "memory");
        } else {
            asm volatile("s_waitcnt vmcnt(0)" ::: "memory");
        }
        __builtin_amdgcn_sched_barrier(0);
        const char* lA = lds + cur * BUFB;
        const char* lB = lA + MT * 2048;
        #pragma unroll
        for (int ks = 0; ks < 2; ++ks) {
            short8 av[MT], bv[4];
            const int rlo = lane & 15;
            const int chi = ks * 4 + (lane >> 4);
            #pragma unroll
            for (int m = 0; m < MT; ++m) {
                int r = m * 16 + rlo;
                av[m] = *(const short8*)(lA + r * 128 + ((chi ^ (r & 7)) << 4));
            }
            #pragma unroll
            for (int n = 0; n < 4; ++n) {
                int r = n * 16 + rlo;
                bv[n] = *(const short8*)(lB + r * 128 + ((chi ^ (r & 7)) << 4));
            }
            #pragma unroll
            for (int m = 0; m < MT; ++m)
                #pragma unroll
                for (int n = 0; n < 4; ++n)
                    acc[m][n] = __builtin_amdgcn_mfma_f32_16x16x32_bf16(
                        av[m], bv[n], acc[m][n], 0, 0, 0);
        }
    }

    const int c_l = lane & 15, r_q = (lane >> 4) * 4;
    #pragma unroll
    for (int m = 0; m < MT; ++m) {
        #pragma unroll
        for (int reg = 0; reg < 4; ++reg) {
            int r_ = tm * (MT * 16) + m * 16 + r_q + reg;
            if (r_ < M) {
                int r2 = r_;
                if (CLS_SWAP) {
                    int bb = r_ / 25, rem = r_ % 25;
                    if (rem % 5 == 0) r2 = bb * 25 + ((rem / 5 + 1) % 5) * 5;
                }
                #pragma unroll
                for (int n = 0; n < 4; ++n) {
                    int cc_ = tn * 64 + n * 16 + c_l;
                    float v = acc[m][n][reg];
                    if (HAS_BIAS) v += bias[cc_];
                    if (HAS_RES) v += res[(size_t)r_ * N + cc_];
                    if (OUT_BF16) ((ushort_t*)Cv)[(size_t)r2 * N + cc_] = f2bf(v);
                    else          ((float*)Cv)[(size_t)r2 * N + cc_] = v;
                    if (BUILD_G) {
                        int b = r_ / 20, t = r_ % 20;
                        float gval = v + temb[t * 1536 + cc_] +
                                     ts[b] * w_num[cc_] + b_num[cc_];
                        g_out[(size_t)(b * 25 + (t / 4) * 5 + (t % 4) + 1) * 1536 + cc_] = gval;
                    }
                }
            }
        }
    }
}

// xr = AP @ WRC^T + BC2 (f32) + BUILD_G
__global__ __launch_bounds__(64) void xr_kernel(
    const ushort_t* __restrict__ AP, const ushort_t* __restrict__ WRC,
    float* __restrict__ XR, const float* __restrict__ BC2,
    float* __restrict__ GA, const float* __restrict__ temb,
    const float* __restrict__ ts, const float* __restrict__ w_num,
    const float* __restrict__ b_num) {
    __shared__ __align__(16) char lds[24576];
    gemm_tile<2, false, true, false, false, true>(
        lds, threadIdx.x, blockIdx.x, blockIdx.y, AP, WRC, XR, BC2, nullptr,
        160, 1536, 768, 768, GA, temb, ts, w_num, b_num);
}

// qkv split-K x2 (f32 halves)
__global__ __launch_bounds__(64) void qkv_kernel(
    const ushort_t* __restrict__ HN, const ushort_t* __restrict__ WQ,
    float* __restrict__ C0, float* __restrict__ C1) {
    __shared__ __align__(16) char lds[32768];
    int tn = blockIdx.x, tmh = blockIdx.y;
    int half = tmh >> 2, tm = tmh & 3;
    gemm_tile<4, false, false, false, false, false>(
        lds, threadIdx.x, tn, tm, HN + half * 768, WQ + half * 768,
        half ? C1 : C0, nullptr, nullptr, 200, 4608, 768, 1536,
        nullptr, nullptr, nullptr, nullptr, nullptr);
}

// proj: gdst = OBF @ WC^T + BC + gsrc, cls-swap (f32 out)
__global__ __launch_bounds__(64) void proj_kernel(
    const ushort_t* __restrict__ OBF, const ushort_t* __restrict__ WC,
    float* __restrict__ gdst, const float* __restrict__ BC,
    const float* __restrict__ gsrc) {
    __shared__ __align__(16) char lds[24576];
    gemm_tile<2, false, true, true, true, false>(
        lds, threadIdx.x, blockIdx.x, blockIdx.y, OBF, WC, gdst, BC, gsrc,
        200, 1536, 1536, 1536, nullptr, nullptr, nullptr, nullptr, nullptr);
}

// ---------------------------------------------------------------------------
// LayerNorm over D=1536 -> bf16 (unchanged)
// ---------------------------------------------------------------------------
__global__ __launch_bounds__(256) void ln_kernel(
    const float* __restrict__ g, const float* __restrict__ gamma,
    const float* __restrict__ beta, ushort_t* __restrict__ hn) {
    int r = blockIdx.x, tid = threadIdx.x;
    const float* x = g + (size_t)r * 1536;
    float v[6], s = 0.f, s2 = 0.f;
    #pragma unroll
    for (int j = 0; j < 6; ++j) {
        v[j] = x[tid + j * 256];
        s += v[j]; s2 += v[j] * v[j];
    }
    #pragma unroll
    for (int m = 1; m < 64; m <<= 1) { s += __shfl_xor(s, m); s2 += __shfl_xor(s2, m); }
    __shared__ float red[8];
    int wid = tid >> 6;
    if ((tid & 63) == 0) { red[wid] = s; red[4 + wid] = s2; }
    __syncthreads();
    s  = red[0] + red[1] + red[2] + red[3];
    s2 = red[4] + red[5] + red[6] + red[7];
    float mean = s * (1.0f / 1536.0f);
    float var  = s2 * (1.0f / 1536.0f) - mean * mean;
    float rstd = rsqrtf(var + 1e-5f);
    #pragma unroll
    for (int j = 0; j < 6; ++j) {
        int d = tid + j * 256;
        float y = (v[j] - mean) * rstd * gamma[d] + beta[d];
        hn[(size_t)r * 1536 + d] = f2bf(y);
    }
}

// ---------------------------------------------------------------------------
// Attention: sums split-K halves (unchanged)
// ---------------------------------------------------------------------------
__global__ __launch_bounds__(64) void attn_kernel(
    const float* __restrict__ qA, const float* __restrict__ qB,
    ushort_t* __restrict__ o) {
    int gid = blockIdx.x;
    int h = gid % 12, gg = gid / 12;
    int l = threadIdx.x;
    size_t off = (size_t)gg * 5 * 4608 + h * 128 + 2 * l;
    const float* b0 = qA + off;
    const float* b1 = qB + off;
    float q[5][2], k[5][2], v[5][2];
    #pragma unroll
    for (int tt = 0; tt < 5; ++tt) {
        float2 q0 = *(const float2*)(b0 + tt * 4608);
        float2 q1 = *(const float2*)(b1 + tt * 4608);
        float2 k0 = *(const float2*)(b0 + tt * 4608 + 1536);
        float2 k1 = *(const float2*)(b1 + tt * 4608 + 1536);
        float2 v0 = *(const float2*)(b0 + tt * 4608 + 3072);
        float2 v1 = *(const float2*)(b1 + tt * 4608 + 3072);
        q[tt][0] = q0.x + q1.x; q[tt][1] = q0.y + q1.y;
        k[tt][0] = k0.x + k1.x; k[tt][1] = k0.y + k1.y;
        v[tt][0] = v0.x + v1.x; v[tt][1] = v0.y + v1.y;
    }
    float sc[5][5];
    #pragma unroll
    for (int i = 0; i < 5; ++i)
        #pragma unroll
        for (int j = 0; j < 5; ++j)
            sc[i][j] = q[i][0] * k[j][0] + q[i][1] * k[j][1];
    #pragma unroll
    for (int m = 1; m < 64; m <<= 1)
        #pragma unroll
        for (int i = 0; i < 5; ++i)
            #pragma unroll
            for (int j = 0; j < 5; ++j)
                sc[i][j] += __shfl_xor(sc[i][j], m);
    const float scale = 0.08838834764831845f;
    float a_[5][5];
    #pragma unroll
    for (int i = 0; i < 5; ++i) {
        float mx = -1e30f;
        #pragma unroll
        for (int j = 0; j < 5; ++j) mx = fmaxf(mx, sc[i][j]);
        float sum = 0.f;
        #pragma unroll
        for (int j = 0; j < 5; ++j) { a_[i][j] = __expf((sc[i][j] - mx) * scale); sum += a_[i][j]; }
        float inv = 1.0f / sum;
        #pragma unroll
        for (int j = 0; j < 5; ++j) a_[i][j] *= inv;
    }
    #pragma unroll
    for (int i = 0; i < 5; ++i) {
        float o0 = 0.f, o1 = 0.f;
        #pragma unroll
        for (int j = 0; j < 5; ++j) { o0 += a_[i][j] * v[j][0]; o1 += a_[i][j] * v[j][1]; }
        ushort2 w; w.x = f2bf(o0); w.y = f2bf(o1);
        *(ushort2*)(o + (size_t)(gg * 5 + i) * 1536 + h * 128 + 2 * l) = w;
    }
}

// ---------------------------------------------------------------------------
// Head (unchanged)
// ---------------------------------------------------------------------------
__global__ __launch_bounds__(64) void head_kernel(
    const float* __restrict__ gfin, const float* __restrict__ xr,
    const float* __restrict__ w_head, const float* __restrict__ b_head,
    float* __restrict__ out) {
    int b = blockIdx.x, l = threadIdx.x;
    const float* gv = gfin + (size_t)(b * 25 + 24) * 1536;
    const float* xv = xr + (size_t)(b * 20 + 19) * 1536;
    float acc[7] = {0, 0, 0, 0, 0, 0, 0};
    for (int d = l; d < 1536; d += 64) {
        float xval = gv[d] + xv[d];
        #pragma unroll
        for (int c = 0; c < 7; ++c) acc[c] += xval * w_head[c * 1536 + d];
    }
    #pragma unroll
    for (int c = 0; c < 7; ++c)
        #pragma unroll
        for (int m = 1; m < 64; m <<= 1) acc[c] += __shfl_xor(acc[c], m);
    if (l == 0) {
        #pragma unroll
        for (int c = 0; c < 7; ++c) out[b * 7 + c] = acc[c] + b_head[c];
    }
}

// ---------------------------------------------------------------------------
// Workspace layout (bytes)
// ---------------------------------------------------------------------------
#define OFF_WQ    0u          // 14155776
#define OFF_WF    14155776u   // 4718592
#define OFF_WR    18874368u   // 4718592
#define OFF_WCVT  23592960u   // 2359296
#define OFF_WTT   25952256u   // 4718592
#define OFF_WC    30670848u   // 4718592
#define OFF_WRC   35389440u   // 2359296
#define OFF_BC    37748736u   // 6144
#define OFF_BC2   37754880u   // 6144
#define OFF_AP    37761024u   // 245760
#define OFF_XR    38006784u   // 983040
#define OFF_GA    38989824u   // 1228800
#define OFF_GB    40218624u   // 1228800
#define OFF_HN    41447424u   // 614400
#define OFF_QKV0  42061824u   // 3686400
#define OFF_QKV1  45748224u   // 3686400
#define OFF_OBF   49434624u   // 614400

extern "C" void kernel_launch(void* const* d_in, const int* in_sizes, int n_in,
                              void* d_out, int out_size, void* d_ws, size_t ws_size,
                              hipStream_t stream) {
    const float* x      = (const float*)d_in[0];
    const float* ts     = (const float*)d_in[1];
    const float* conv_w = (const float*)d_in[2];
    const float* conv_b = (const float*)d_in[3];
    const float* w_red  = (const float*)d_in[4];
    const float* b_red  = (const float*)d_in[5];
    const float* w_num  = (const float*)d_in[6];
    const float* b_num  = (const float*)d_in[7];
    const float* temb   = (const float*)d_in[8];
    const float* cls    = (const float*)d_in[9];
    const float* ln_g   = (const float*)d_in[10];
    const float* ln_b   = (const float*)d_in[11];
    const float* w_qkv  = (const float*)d_in[12];
    const float* w_tp   = (const float*)d_in[13];
    const float* b_tp   = (const float*)d_in[14];
    const float* w_tf   = (const float*)d_in[15];
    const float* b_tf   = (const float*)d_in[16];
    const float* w_head = (const float*)d_in[17];
    const float* b_head = (const float*)d_in[18];

    char* ws = (char*)d_ws;
    ushort_t* WQ   = (ushort_t*)(ws + OFF_WQ);
    ushort_t* WF   = (ushort_t*)(ws + OFF_WF);
    ushort_t* WR   = (ushort_t*)(ws + OFF_WR);
    ushort_t* WCVT = (ushort_t*)(ws + OFF_WCVT);
    ushort_t* WTT  = (ushort_t*)(ws + OFF_WTT);
    ushort_t* WC   = (ushort_t*)(ws + OFF_WC);
    ushort_t* WRC  = (ushort_t*)(ws + OFF_WRC);
    float*    BC   = (float*)(ws + OFF_BC);
    float*    BC2  = (float*)(ws + OFF_BC2);
    ushort_t* AP   = (ushort_t*)(ws + OFF_AP);
    float*    XR   = (float*)(ws + OFF_XR);
    float*    GA   = (float*)(ws + OFF_GA);
    float*    GB   = (float*)(ws + OFF_GB);
    ushort_t* HN   = (ushort_t*)(ws + OFF_HN);
    float*    QKV0 = (float*)(ws + OFF_QKV0);
    float*    QKV1 = (float*)(ws + OFF_QKV1);
    ushort_t* OBF  = (ushort_t*)(ws + OFF_OBF);

    // 1) prep: pool + weight prep (one launch, relaxed VGPR bound)
    prep_kernel<<<7336, 256, 0, stream>>>(x, w_qkv, w_tf, w_red, conv_w, w_tp,
                                          b_tp, b_tf, conv_b, b_red, cls,
                                          AP, WQ, WF, WR, WCVT, WTT, BC, BC2, GA);
    // 2) Wc + WRC (one 128-tile launch)
    wcf_kernel<<<216, 256, 0, stream>>>(WF, WTT, WR, WCVT, WC, WRC);
    // 3) xr = AP @ WRC^T + BC2 (f32) + build g rows
    xr_kernel<<<dim3(24, 5), 64, 0, stream>>>(AP, WRC, XR, BC2, GA,
                                              temb, ts, w_num, b_num);
    // 4) loop
    float* gsrc = GA;
    float* gdst = GB;
    for (int it = 0; it < 4; ++it) {
        ln_kernel<<<200, 256, 0, stream>>>(gsrc, ln_g, ln_b, HN);
        qkv_kernel<<<dim3(72, 8), 64, 0, stream>>>(HN, WQ, QKV0, QKV1);
        attn_kernel<<<480, 64, 0, stream>>>(QKV0, QKV1, OBF);
        proj_kernel<<<dim3(24, 7), 64, 0, stream>>>(OBF, WC, gdst, BC, gsrc);
        float* tmp = gsrc; gsrc = gdst; gdst = tmp;
    }
    // 5) head
    head_kernel<<<8, 64, 0, stream>>>(gsrc, XR, w_head, b_head, (float*)d_out);
}

// Round 20
// 199.580 us; speedup vs baseline: 1.0059x; 1.0059x over previous
//
#include <hip/hip_runtime.h>

typedef __attribute__((ext_vector_type(8))) short short8;
typedef __attribute__((ext_vector_type(8))) unsigned short ushort8;
typedef __attribute__((ext_vector_type(4))) float f32x4;
typedef unsigned short ushort_t;

__device__ __forceinline__ ushort_t f2bf(float f) {
    unsigned u = __builtin_bit_cast(unsigned, f);
    u += 0x7fffu + ((u >> 16) & 1u);
    return (ushort_t)(u >> 16);
}

__device__ __forceinline__ void load_lds16b(const void* gp, void* lp) {
    __builtin_amdgcn_global_load_lds(
        (const __attribute__((address_space(1))) void*)gp,
        (__attribute__((address_space(3))) void*)lp, 16, 0, 0);
}

// ---------------------------------------------------------------------------
// prep kernel = pool + weight prep, grid-compressed (3016 blocks).
//  [0,480)       pool: block = (bt,c) (r19 body)
//  [480,1920)    cvt f32->bf16 x4 units/block: w_qkv, w_tf, w_red
//  [1920,2496)   transpose+cvt w_tp -> WTT
//  [2496,2784)   transpose+cvt conv_w -> WCVT
//  [2784,2824)   cls rows -> GA
//  [2824,2920)   BC[i]  = w_tf[i,:].b_tp + b_tf[i]
//  [2920,3016)   BC2[j] = w_red[j,:].conv_b + b_red[j]
// ---------------------------------------------------------------------------
__global__ __launch_bounds__(256, 2) void prep_kernel(
    const float* __restrict__ x, const float* __restrict__ w_qkv,
    const float* __restrict__ w_tf, const float* __restrict__ w_red,
    const float* __restrict__ conv_w, const float* __restrict__ w_tp,
    const float* __restrict__ b_tp, const float* __restrict__ b_tf,
    const float* __restrict__ conv_b, const float* __restrict__ b_red,
    const float* __restrict__ cls,
    ushort_t* __restrict__ AP, ushort_t* __restrict__ WQ,
    ushort_t* __restrict__ WF, ushort_t* __restrict__ WR,
    ushort_t* __restrict__ WCVT, ushort_t* __restrict__ WTT,
    float* __restrict__ BC, float* __restrict__ BC2,
    float* __restrict__ GA) {
    __shared__ __align__(16) float smem[64 * 68];
    int blk = blockIdx.x, tid = threadIdx.x;
    if (blk < 480) {
        int bt = blk / 3, c = blk % 3;
        int b = bt / 20, t = bt % 20;
        int w = tid >> 6, lane = tid & 63;
        int cl = lane < 56 ? lane : 55;
        const float* base = x + (size_t)((b * 3 + c) * 20 + t) * 50176
                              + (size_t)w * 224 + 4 * cl;
        f32x4 acc4[4];
        #pragma unroll
        for (int q = 0; q < 4; ++q) acc4[q] = (f32x4){0.f, 0.f, 0.f, 0.f};
        #pragma unroll
        for (int b16 = 0; b16 < 4; ++b16) {
            const int cnt = (b16 == 3) ? 8 : 16;
            f32x4 v[16];
            #pragma unroll
            for (int u = 0; u < 16; ++u) {
                if (u < cnt) {
                    int j = b16 * 16 + u;
                    v[u] = *(const f32x4*)(base + (size_t)j * 896);
                }
            }
            #pragma unroll
            for (int u = 0; u < 16; ++u)
                if (u < cnt) acc4[u & 3] += v[u];
        }
        if (lane >= 56) {
            #pragma unroll
            for (int q = 0; q < 4; ++q) acc4[q] = (f32x4){0.f, 0.f, 0.f, 0.f};
        }
        #pragma unroll
        for (int q = 0; q < 4; ++q) {
            #pragma unroll
            for (int m = 4; m <= 32; m <<= 1) {
                acc4[q][0] += __shfl_xor(acc4[q][0], m);
                acc4[q][1] += __shfl_xor(acc4[q][1], m);
                acc4[q][2] += __shfl_xor(acc4[q][2], m);
                acc4[q][3] += __shfl_xor(acc4[q][3], m);
            }
        }
        if (lane < 4) {
            #pragma unroll
            for (int q = 0; q < 4; ++q) {
                int i = w + 4 * q;
                ushort4 o;
                o.x = f2bf(acc4[q][0] * (1.f / 196.f));
                o.y = f2bf(acc4[q][1] * (1.f / 196.f));
                o.z = f2bf(acc4[q][2] * (1.f / 196.f));
                o.w = f2bf(acc4[q][3] * (1.f / 196.f));
                *(ushort4*)(AP + (size_t)bt * 768 + c * 256 + i * 16 + 4 * lane) = o;
            }
        }
    } else if (blk < 1920) {
        // 4 units of 2048 elems per block; batch all 8 loads before stores
        f32x4 va[4], vb[4];
        ushort_t* dst[4];
        long off[4];
        #pragma unroll
        for (int it = 0; it < 4; ++it) {
            long c = ((long)(blk - 480) * 4 + it) * 2048 + tid * 8;
            const float* s; ushort_t* d; long i;
            if (c < 7077888)       { s = w_qkv; d = WQ; i = c; }
            else if (c < 9437184)  { s = w_tf;  d = WF; i = c - 7077888; }
            else                   { s = w_red; d = WR; i = c - 9437184; }
            va[it] = *(const f32x4*)(s + i);
            vb[it] = *(const f32x4*)(s + i + 4);
            dst[it] = d; off[it] = i;
        }
        #pragma unroll
        for (int it = 0; it < 4; ++it) {
            ushort8 o;
            o[0] = f2bf(va[it][0]); o[1] = f2bf(va[it][1]);
            o[2] = f2bf(va[it][2]); o[3] = f2bf(va[it][3]);
            o[4] = f2bf(vb[it][0]); o[5] = f2bf(vb[it][1]);
            o[6] = f2bf(vb[it][2]); o[7] = f2bf(vb[it][3]);
            *(ushort8*)(dst[it] + off[it]) = o;
        }
    } else if (blk < 2496) {
        int tb = blk - 1920;
        int bi = tb / 24, bj = tb % 24;
        int r0 = (tid >> 4) << 2;
        int c0 = (tid & 15) << 2;
        #pragma unroll
        for (int rr = 0; rr < 4; ++rr) {
            f32x4 v = *(const f32x4*)(w_tp + (size_t)(bi * 64 + r0 + rr) * 1536 + bj * 64 + c0);
            smem[(r0 + rr) * 68 + c0 + 0] = v[0];
            smem[(r0 + rr) * 68 + c0 + 1] = v[1];
            smem[(r0 + rr) * 68 + c0 + 2] = v[2];
            smem[(r0 + rr) * 68 + c0 + 3] = v[3];
        }
        __syncthreads();
        #pragma unroll
        for (int rr = 0; rr < 4; ++rr) {
            int jj = r0 + rr;
            ushort4 o;
            o.x = f2bf(smem[(c0 + 0) * 68 + jj]);
            o.y = f2bf(smem[(c0 + 1) * 68 + jj]);
            o.z = f2bf(smem[(c0 + 2) * 68 + jj]);
            o.w = f2bf(smem[(c0 + 3) * 68 + jj]);
            *(ushort4*)(WTT + (size_t)(bj * 64 + jj) * 1536 + bi * 64 + c0) = o;
        }
    } else if (blk < 2784) {
        int tb = blk - 2496;
        int bi = tb / 12, bj = tb % 12;
        int r0 = (tid >> 4) << 2;
        int c0 = (tid & 15) << 2;
        #pragma unroll
        for (int rr = 0; rr < 4; ++rr) {
            f32x4 v = *(const f32x4*)(conv_w + (size_t)(bi * 64 + r0 + rr) * 768 + bj * 64 + c0);
            smem[(r0 + rr) * 68 + c0 + 0] = v[0];
            smem[(r0 + rr) * 68 + c0 + 1] = v[1];
            smem[(r0 + rr) * 68 + c0 + 2] = v[2];
            smem[(r0 + rr) * 68 + c0 + 3] = v[3];
        }
        __syncthreads();
        #pragma unroll
        for (int rr = 0; rr < 4; ++rr) {
            int jj = r0 + rr;
            ushort4 o;
            o.x = f2bf(smem[(c0 + 0) * 68 + jj]);
            o.y = f2bf(smem[(c0 + 1) * 68 + jj]);
            o.z = f2bf(smem[(c0 + 2) * 68 + jj]);
            o.w = f2bf(smem[(c0 + 3) * 68 + jj]);
            *(ushort4*)(WCVT + (size_t)(bj * 64 + jj) * 1536 + bi * 64 + c0) = o;
        }
    } else if (blk < 2824) {
        int cblk = blk - 2784;
        int b = cblk / 5, n = cblk % 5;
        size_t row = (size_t)(b * 25 + n * 5) * 1536;
        #pragma unroll
        for (int j = 0; j < 6; ++j) {
            int d = tid + j * 256;
            GA[row + d] = cls[n * 1536 + d];
        }
    } else if (blk < 2920) {
        int bb = blk - 2824;
        int row = bb * 16 + (tid >> 4);
        int sub = tid & 15;
        float acc = 0.f;
        for (int j = 0; j < 96; ++j) {
            int k = sub + j * 16;
            acc += w_tf[(size_t)row * 1536 + k] * b_tp[k];
        }
        acc += __shfl_xor(acc, 1); acc += __shfl_xor(acc, 2);
        acc += __shfl_xor(acc, 4); acc += __shfl_xor(acc, 8);
        if (sub == 0) BC[row] = acc + b_tf[row];
    } else {
        int bb = blk - 2920;
        int row = bb * 16 + (tid >> 4);
        int sub = tid & 15;
        float acc = 0.f;
        for (int j = 0; j < 48; ++j) {
            int n0 = sub + j * 16;
            acc += w_red[(size_t)row * 1536 + n0] * conv_b[n0];
            acc += w_red[(size_t)row * 1536 + n0 + 768] * conv_b[n0 + 768];
        }
        acc += __shfl_xor(acc, 1); acc += __shfl_xor(acc, 2);
        acc += __shfl_xor(acc, 4); acc += __shfl_xor(acc, 8);
        if (sub == 0) BC2[row] = acc + b_red[row];
    }
}

// ---------------------------------------------------------------------------
// 128x128-tile 4-wave GEMM tile (r16, verified)
// ---------------------------------------------------------------------------
template <bool OUT_BF16>
__device__ __forceinline__ void gemm128_tile(
    char* lds, const ushort_t* __restrict__ A, const ushort_t* __restrict__ B,
    void* __restrict__ Cv, int M, int N, int K, int KS, int tn, int tm) {
    const int tid = threadIdx.x;
    const int lane = tid & 63;
    const int w = tid >> 6;
    const int wr = w >> 1, wc = w & 1;

    f32x4 acc[4][4];
    #pragma unroll
    for (int m = 0; m < 4; ++m)
        #pragma unroll
        for (int n = 0; n < 4; ++n)
            acc[m][n] = (f32x4){0.f, 0.f, 0.f, 0.f};

    const int nK = K >> 6;
    const int rbase = lane >> 3, cc = lane & 7;

    auto stage = [&](int k0, int buf) {
        char* lA = lds + buf * 32768;
        char* lB = lA + 16384;
        #pragma unroll
        for (int j = 0; j < 4; ++j) {
            int row = w * 32 + j * 8 + rbase;
            int cf = cc ^ (row & 7);
            int ga = tm * 128 + row; if (ga > M - 1) ga = M - 1;
            load_lds16b(A + (size_t)ga * KS + (k0 + cf * 8),
                        lA + (w * 32 + j * 8) * 128);
        }
        #pragma unroll
        for (int j = 0; j < 4; ++j) {
            int row = w * 32 + j * 8 + rbase;
            int cf = cc ^ (row & 7);
            load_lds16b(B + (size_t)(tn * 128 + row) * KS + (k0 + cf * 8),
                        lB + (w * 32 + j * 8) * 128);
        }
    };

    stage(0, 0);
    asm volatile("s_waitcnt vmcnt(0)" ::: "memory");
    __builtin_amdgcn_s_barrier();
    __builtin_amdgcn_sched_barrier(0);
    for (int t = 0; t < nK; ++t) {
        int cur = t & 1;
        if (t + 1 < nK) stage((t + 1) << 6, cur ^ 1);
        __builtin_amdgcn_sched_barrier(0);
        const char* lA = lds + cur * 32768;
        const char* lB = lA + 16384;
        #pragma unroll
        for (int ks = 0; ks < 2; ++ks) {
            short8 av[4], bv[4];
            const int rlo = lane & 15;
            const int chi = ks * 4 + (lane >> 4);
            #pragma unroll
            for (int m = 0; m < 4; ++m) {
                int r = wr * 64 + m * 16 + rlo;
                av[m] = *(const short8*)(lA + r * 128 + ((chi ^ (r & 7)) << 4));
            }
            #pragma unroll
            for (int n = 0; n < 4; ++n) {
                int r = wc * 64 + n * 16 + rlo;
                bv[n] = *(const short8*)(lB + r * 128 + ((chi ^ (r & 7)) << 4));
            }
            #pragma unroll
            for (int m = 0; m < 4; ++m)
                #pragma unroll
                for (int n = 0; n < 4; ++n)
                    acc[m][n] = __builtin_amdgcn_mfma_f32_16x16x32_bf16(
                        av[m], bv[n], acc[m][n], 0, 0, 0);
        }
        asm volatile("s_waitcnt vmcnt(0)" ::: "memory");
        __builtin_amdgcn_s_barrier();
        __builtin_amdgcn_sched_barrier(0);
    }

    const int c_l = lane & 15, r_q = (lane >> 4) * 4;
    #pragma unroll
    for (int m = 0; m < 4; ++m) {
        #pragma unroll
        for (int reg = 0; reg < 4; ++reg) {
            int r_ = tm * 128 + wr * 64 + m * 16 + r_q + reg;
            if (r_ < M) {
                #pragma unroll
                for (int n = 0; n < 4; ++n) {
                    int cc_ = tn * 128 + wc * 64 + n * 16 + c_l;
                    float v = acc[m][n][reg];
                    if (OUT_BF16) ((ushort_t*)Cv)[(size_t)r_ * N + cc_] = f2bf(v);
                    else          ((float*)Cv)[(size_t)r_ * N + cc_] = v;
                }
            }
        }
    }
}

// Wc (144 tiles) + WRC (72 tiles), one 128-tile launch
__global__ __launch_bounds__(256) void wcf_kernel(
    const ushort_t* __restrict__ WF, const ushort_t* __restrict__ WTT,
    const ushort_t* __restrict__ WR, const ushort_t* __restrict__ WCVT,
    ushort_t* __restrict__ WC, ushort_t* __restrict__ WRC) {
    __shared__ __align__(16) char lds[65536];
    int task = blockIdx.x;
    if (task < 144)
        gemm128_tile<true>(lds, WF, WTT, WC, 1536, 1536, 1536, 1536,
                           task % 12, task / 12);
    else {
        int t2 = task - 144;
        gemm128_tile<true>(lds, WR, WCVT, WRC, 1536, 768, 1536, 1536,
                           t2 % 6, t2 / 6);
    }
}

// ---------------------------------------------------------------------------
// single-wave GEMM tile (round-13, unchanged)
// ---------------------------------------------------------------------------
template <int MT, bool OUT_BF16, bool HAS_BIAS, bool HAS_RES, bool CLS_SWAP, bool BUILD_G>
__device__ __forceinline__ void gemm_tile(
    char* lds, int lane, int tn, int tm,
    const ushort_t* __restrict__ A, const ushort_t* __restrict__ B,
    void* __restrict__ Cv, const float* __restrict__ bias,
    const float* __restrict__ res, int M, int N, int K, int KS,
    float* __restrict__ g_out, const float* __restrict__ temb,
    const float* __restrict__ ts, const float* __restrict__ w_num,
    const float* __restrict__ b_num) {
    constexpr int BUFB = MT * 2048 + 8192;

    f32x4 acc[MT][4];
    #pragma unroll
    for (int m = 0; m < MT; ++m)
        #pragma unroll
        for (int n = 0; n < 4; ++n)
            acc[m][n] = (f32x4){0.f, 0.f, 0.f, 0.f};

    const int nK = K >> 6;
    const int rbase = lane >> 3, cc = lane & 7;

    auto stage = [&](int k0, int buf) {
        char* lA = lds + buf * BUFB;
        char* lB = lA + MT * 2048;
        #pragma unroll
        for (int j = 0; j < MT * 2; ++j) {
            int row = j * 8 + rbase;
            int cf = cc ^ (row & 7);
            int ga = tm * (MT * 16) + row; if (ga > M - 1) ga = M - 1;
            load_lds16b(A + (size_t)ga * KS + (k0 + cf * 8), lA + j * 1024);
        }
        #pragma unroll
        for (int j = 0; j < 8; ++j) {
            int row = j * 8 + rbase;
            int cf = cc ^ (row & 7);
            load_lds16b(B + (size_t)(tn * 64 + row) * KS + (k0 + cf * 8), lB + j * 1024);
        }
    };

    stage(0, 0);
    for (int t = 0; t < nK; ++t) {
        int cur = t & 1;
        if (t + 1 < nK) {
            stage((t + 1) << 6, cur ^ 1);
            if constexpr (MT == 2) asm volatile("s_waitcnt vmcnt(12)" ::: "memory");
            else                   asm volatile("s_waitcnt vmcnt(16)" ::: "memory");
        } else {
            asm volatile("s_waitcnt vmcnt(0)" ::: "memory");
        }
        __builtin_amdgcn_sched_barrier(0);
        const char* lA = lds + cur * BUFB;
        const char* lB = lA + MT * 2048;
        #pragma unroll
        for (int ks = 0; ks < 2; ++ks) {
            short8 av[MT], bv[4];
            const int rlo = lane & 15;
            const int chi = ks * 4 + (lane >> 4);
            #pragma unroll
            for (int m = 0; m < MT; ++m) {
                int r = m * 16 + rlo;
                av[m] = *(const short8*)(lA + r * 128 + ((chi ^ (r & 7)) << 4));
            }
            #pragma unroll
            for (int n = 0; n < 4; ++n) {
                int r = n * 16 + rlo;
                bv[n] = *(const short8*)(lB + r * 128 + ((chi ^ (r & 7)) << 4));
            }
            #pragma unroll
            for (int m = 0; m < MT; ++m)
                #pragma unroll
                for (int n = 0; n < 4; ++n)
                    acc[m][n] = __builtin_amdgcn_mfma_f32_16x16x32_bf16(
                        av[m], bv[n], acc[m][n], 0, 0, 0);
        }
    }

    const int c_l = lane & 15, r_q = (lane >> 4) * 4;
    #pragma unroll
    for (int m = 0; m < MT; ++m) {
        #pragma unroll
        for (int reg = 0; reg < 4; ++reg) {
            int r_ = tm * (MT * 16) + m * 16 + r_q + reg;
            if (r_ < M) {
                int r2 = r_;
                if (CLS_SWAP) {
                    int bb = r_ / 25, rem = r_ % 25;
                    if (rem % 5 == 0) r2 = bb * 25 + ((rem / 5 + 1) % 5) * 5;
                }
                #pragma unroll
                for (int n = 0; n < 4; ++n) {
                    int cc_ = tn * 64 + n * 16 + c_l;
                    float v = acc[m][n][reg];
                    if (HAS_BIAS) v += bias[cc_];
                    if (HAS_RES) v += res[(size_t)r_ * N + cc_];
                    if (OUT_BF16) ((ushort_t*)Cv)[(size_t)r2 * N + cc_] = f2bf(v);
                    else          ((float*)Cv)[(size_t)r2 * N + cc_] = v;
                    if (BUILD_G) {
                        int b = r_ / 20, t = r_ % 20;
                        float gval = v + temb[t * 1536 + cc_] +
                                     ts[b] * w_num[cc_] + b_num[cc_];
                        g_out[(size_t)(b * 25 + (t / 4) * 5 + (t % 4) + 1) * 1536 + cc_] = gval;
                    }
                }
            }
        }
    }
}

// xr = AP @ WRC^T + BC2 (f32) + BUILD_G
__global__ __launch_bounds__(64) void xr_kernel(
    const ushort_t* __restrict__ AP, const ushort_t* __restrict__ WRC,
    float* __restrict__ XR, const float* __restrict__ BC2,
    float* __restrict__ GA, const float* __restrict__ temb,
    const float* __restrict__ ts, const float* __restrict__ w_num,
    const float* __restrict__ b_num) {
    __shared__ __align__(16) char lds[24576];
    gemm_tile<2, false, true, false, false, true>(
        lds, threadIdx.x, blockIdx.x, blockIdx.y, AP, WRC, XR, BC2, nullptr,
        160, 1536, 768, 768, GA, temb, ts, w_num, b_num);
}

// qkv split-K x2 (f32 halves)
__global__ __launch_bounds__(64) void qkv_kernel(
    const ushort_t* __restrict__ HN, const ushort_t* __restrict__ WQ,
    float* __restrict__ C0, float* __restrict__ C1) {
    __shared__ __align__(16) char lds[32768];
    int tn = blockIdx.x, tmh = blockIdx.y;
    int half = tmh >> 2, tm = tmh & 3;
    gemm_tile<4, false, false, false, false, false>(
        lds, threadIdx.x, tn, tm, HN + half * 768, WQ + half * 768,
        half ? C1 : C0, nullptr, nullptr, 200, 4608, 768, 1536,
        nullptr, nullptr, nullptr, nullptr, nullptr);
}

// proj: gdst = OBF @ WC^T + BC + gsrc, cls-swap (f32 out)
__global__ __launch_bounds__(64) void proj_kernel(
    const ushort_t* __restrict__ OBF, const ushort_t* __restrict__ WC,
    float* __restrict__ gdst, const float* __restrict__ BC,
    const float* __restrict__ gsrc) {
    __shared__ __align__(16) char lds[24576];
    gemm_tile<2, false, true, true, true, false>(
        lds, threadIdx.x, blockIdx.x, blockIdx.y, OBF, WC, gdst, BC, gsrc,
        200, 1536, 1536, 1536, nullptr, nullptr, nullptr, nullptr, nullptr);
}

// ---------------------------------------------------------------------------
// LayerNorm over D=1536 -> bf16 (unchanged)
// ---------------------------------------------------------------------------
__global__ __launch_bounds__(256) void ln_kernel(
    const float* __restrict__ g, const float* __restrict__ gamma,
    const float* __restrict__ beta, ushort_t* __restrict__ hn) {
    int r = blockIdx.x, tid = threadIdx.x;
    const float* x = g + (size_t)r * 1536;
    float v[6], s = 0.f, s2 = 0.f;
    #pragma unroll
    for (int j = 0; j < 6; ++j) {
        v[j] = x[tid + j * 256];
        s += v[j]; s2 += v[j] * v[j];
    }
    #pragma unroll
    for (int m = 1; m < 64; m <<= 1) { s += __shfl_xor(s, m); s2 += __shfl_xor(s2, m); }
    __shared__ float red[8];
    int wid = tid >> 6;
    if ((tid & 63) == 0) { red[wid] = s; red[4 + wid] = s2; }
    __syncthreads();
    s  = red[0] + red[1] + red[2] + red[3];
    s2 = red[4] + red[5] + red[6] + red[7];
    float mean = s * (1.0f / 1536.0f);
    float var  = s2 * (1.0f / 1536.0f) - mean * mean;
    float rstd = rsqrtf(var + 1e-5f);
    #pragma unroll
    for (int j = 0; j < 6; ++j) {
        int d = tid + j * 256;
        float y = (v[j] - mean) * rstd * gamma[d] + beta[d];
        hn[(size_t)r * 1536 + d] = f2bf(y);
    }
}

// ---------------------------------------------------------------------------
// Attention: sums split-K halves (unchanged)
// ---------------------------------------------------------------------------
__global__ __launch_bounds__(64) void attn_kernel(
    const float* __restrict__ qA, const float* __restrict__ qB,
    ushort_t* __restrict__ o) {
    int gid = blockIdx.x;
    int h = gid % 12, gg = gid / 12;
    int l = threadIdx.x;
    size_t off = (size_t)gg * 5 * 4608 + h * 128 + 2 * l;
    const float* b0 = qA + off;
    const float* b1 = qB + off;
    float q[5][2], k[5][2], v[5][2];
    #pragma unroll
    for (int tt = 0; tt < 5; ++tt) {
        float2 q0 = *(const float2*)(b0 + tt * 4608);
        float2 q1 = *(const float2*)(b1 + tt * 4608);
        float2 k0 = *(const float2*)(b0 + tt * 4608 + 1536);
        float2 k1 = *(const float2*)(b1 + tt * 4608 + 1536);
        float2 v0 = *(const float2*)(b0 + tt * 4608 + 3072);
        float2 v1 = *(const float2*)(b1 + tt * 4608 + 3072);
        q[tt][0] = q0.x + q1.x; q[tt][1] = q0.y + q1.y;
        k[tt][0] = k0.x + k1.x; k[tt][1] = k0.y + k1.y;
        v[tt][0] = v0.x + v1.x; v[tt][1] = v0.y + v1.y;
    }
    float sc[5][5];
    #pragma unroll
    for (int i = 0; i < 5; ++i)
        #pragma unroll
        for (int j = 0; j < 5; ++j)
            sc[i][j] = q[i][0] * k[j][0] + q[i][1] * k[j][1];
    #pragma unroll
    for (int m = 1; m < 64; m <<= 1)
        #pragma unroll
        for (int i = 0; i < 5; ++i)
            #pragma unroll
            for (int j = 0; j < 5; ++j)
                sc[i][j] += __shfl_xor(sc[i][j], m);
    const float scale = 0.08838834764831845f;
    float a_[5][5];
    #pragma unroll
    for (int i = 0; i < 5; ++i) {
        float mx = -1e30f;
        #pragma unroll
        for (int j = 0; j < 5; ++j) mx = fmaxf(mx, sc[i][j]);
        float sum = 0.f;
        #pragma unroll
        for (int j = 0; j < 5; ++j) { a_[i][j] = __expf((sc[i][j] - mx) * scale); sum += a_[i][j]; }
        float inv = 1.0f / sum;
        #pragma unroll
        for (int j = 0; j < 5; ++j) a_[i][j] *= inv;
    }
    #pragma unroll
    for (int i = 0; i < 5; ++i) {
        float o0 = 0.f, o1 = 0.f;
        #pragma unroll
        for (int j = 0; j < 5; ++j) { o0 += a_[i][j] * v[j][0]; o1 += a_[i][j] * v[j][1]; }
        ushort2 w; w.x = f2bf(o0); w.y = f2bf(o1);
        *(ushort2*)(o + (size_t)(gg * 5 + i) * 1536 + h * 128 + 2 * l) = w;
    }
}

// ---------------------------------------------------------------------------
// Head (unchanged)
// ---------------------------------------------------------------------------
__global__ __launch_bounds__(64) void head_kernel(
    const float* __restrict__ gfin, const float* __restrict__ xr,
    const float* __restrict__ w_head, const float* __restrict__ b_head,
    float* __restrict__ out) {
    int b = blockIdx.x, l = threadIdx.x;
    const float* gv = gfin + (size_t)(b * 25 + 24) * 1536;
    const float* xv = xr + (size_t)(b * 20 + 19) * 1536;
    float acc[7] = {0, 0, 0, 0, 0, 0, 0};
    for (int d = l; d < 1536; d += 64) {
        float xval = gv[d] + xv[d];
        #pragma unroll
        for (int c = 0; c < 7; ++c) acc[c] += xval * w_head[c * 1536 + d];
    }
    #pragma unroll
    for (int c = 0; c < 7; ++c)
        #pragma unroll
        for (int m = 1; m < 64; m <<= 1) acc[c] += __shfl_xor(acc[c], m);
    if (l == 0) {
        #pragma unroll
        for (int c = 0; c < 7; ++c) out[b * 7 + c] = acc[c] + b_head[c];
    }
}

// ---------------------------------------------------------------------------
// Workspace layout (bytes)
// ---------------------------------------------------------------------------
#define OFF_WQ    0u          // 14155776
#define OFF_WF    14155776u   // 4718592
#define OFF_WR    18874368u   // 4718592
#define OFF_WCVT  23592960u   // 2359296
#define OFF_WTT   25952256u   // 4718592
#define OFF_WC    30670848u   // 4718592
#define OFF_WRC   35389440u   // 2359296
#define OFF_BC    37748736u   // 6144
#define OFF_BC2   37754880u   // 6144
#define OFF_AP    37761024u   // 245760
#define OFF_XR    38006784u   // 983040
#define OFF_GA    38989824u   // 1228800
#define OFF_GB    40218624u   // 1228800
#define OFF_HN    41447424u   // 614400
#define OFF_QKV0  42061824u   // 3686400
#define OFF_QKV1  45748224u   // 3686400
#define OFF_OBF   49434624u   // 614400

extern "C" void kernel_launch(void* const* d_in, const int* in_sizes, int n_in,
                              void* d_out, int out_size, void* d_ws, size_t ws_size,
                              hipStream_t stream) {
    const float* x      = (const float*)d_in[0];
    const float* ts     = (const float*)d_in[1];
    const float* conv_w = (const float*)d_in[2];
    const float* conv_b = (const float*)d_in[3];
    const float* w_red  = (const float*)d_in[4];
    const float* b_red  = (const float*)d_in[5];
    const float* w_num  = (const float*)d_in[6];
    const float* b_num  = (const float*)d_in[7];
    const float* temb   = (const float*)d_in[8];
    const float* cls    = (const float*)d_in[9];
    const float* ln_g   = (const float*)d_in[10];
    const float* ln_b   = (const float*)d_in[11];
    const float* w_qkv  = (const float*)d_in[12];
    const float* w_tp   = (const float*)d_in[13];
    const float* b_tp   = (const float*)d_in[14];
    const float* w_tf   = (const float*)d_in[15];
    const float* b_tf   = (const float*)d_in[16];
    const float* w_head = (const float*)d_in[17];
    const float* b_head = (const float*)d_in[18];

    char* ws = (char*)d_ws;
    ushort_t* WQ   = (ushort_t*)(ws + OFF_WQ);
    ushort_t* WF   = (ushort_t*)(ws + OFF_WF);
    ushort_t* WR   = (ushort_t*)(ws + OFF_WR);
    ushort_t* WCVT = (ushort_t*)(ws + OFF_WCVT);
    ushort_t* WTT  = (ushort_t*)(ws + OFF_WTT);
    ushort_t* WC   = (ushort_t*)(ws + OFF_WC);
    ushort_t* WRC  = (ushort_t*)(ws + OFF_WRC);
    float*    BC   = (float*)(ws + OFF_BC);
    float*    BC2  = (float*)(ws + OFF_BC2);
    ushort_t* AP   = (ushort_t*)(ws + OFF_AP);
    float*    XR   = (float*)(ws + OFF_XR);
    float*    GA   = (float*)(ws + OFF_GA);
    float*    GB   = (float*)(ws + OFF_GB);
    ushort_t* HN   = (ushort_t*)(ws + OFF_HN);
    float*    QKV0 = (float*)(ws + OFF_QKV0);
    float*    QKV1 = (float*)(ws + OFF_QKV1);
    ushort_t* OBF  = (ushort_t*)(ws + OFF_OBF);

    // 1) prep: pool + weight prep (grid-compressed, 3016 blocks)
    prep_kernel<<<3016, 256, 0, stream>>>(x, w_qkv, w_tf, w_red, conv_w, w_tp,
                                          b_tp, b_tf, conv_b, b_red, cls,
                                          AP, WQ, WF, WR, WCVT, WTT, BC, BC2, GA);
    // 2) Wc + WRC (one 128-tile launch)
    wcf_kernel<<<216, 256, 0, stream>>>(WF, WTT, WR, WCVT, WC, WRC);
    // 3) xr = AP @ WRC^T + BC2 (f32) + build g rows
    xr_kernel<<<dim3(24, 5), 64, 0, stream>>>(AP, WRC, XR, BC2, GA,
                                              temb, ts, w_num, b_num);
    // 4) loop
    float* gsrc = GA;
    float* gdst = GB;
    for (int it = 0; it < 4; ++it) {
        ln_kernel<<<200, 256, 0, stream>>>(gsrc, ln_g, ln_b, HN);
        qkv_kernel<<<dim3(72, 8), 64, 0, stream>>>(HN, WQ, QKV0, QKV1);
        attn_kernel<<<480, 64, 0, stream>>>(QKV0, QKV1, OBF);
        proj_kernel<<<dim3(24, 7), 64, 0, stream>>>(OBF, WC, gdst, BC, gsrc);
        float* tmp = gsrc; gsrc = gdst; gdst = tmp;
    }
    // 5) head
    head_kernel<<<8, 64, 0, stream>>>(gsrc, XR, w_head, b_head, (float*)d_out);
}

// Round 21
// 199.018 us; speedup vs baseline: 1.0088x; 1.0028x over previous
//
#include <hip/hip_runtime.h>

typedef __attribute__((ext_vector_type(8))) short short8;
typedef __attribute__((ext_vector_type(8))) unsigned short ushort8;
typedef __attribute__((ext_vector_type(4))) float f32x4;
typedef unsigned short ushort_t;

__device__ __forceinline__ ushort_t f2bf(float f) {
    unsigned u = __builtin_bit_cast(unsigned, f);
    u += 0x7fffu + ((u >> 16) & 1u);
    return (ushort_t)(u >> 16);
}

__device__ __forceinline__ void load_lds16b(const void* gp, void* lp) {
    __builtin_amdgcn_global_load_lds(
        (const __attribute__((address_space(1))) void*)gp,
        (__attribute__((address_space(3))) void*)lp, 16, 0, 0);
}

// ---------------------------------------------------------------------------
// prep kernel (3016 blocks): streaming sections use global_load_lds (loads
// have NO VGPR destination -> deep in-flight queue independent of regalloc).
//  [0,480)       pool: block=(bt,c); 7 chunks x 32 rows double-buffered in
//                LDS (1040B slots); thread (i,j) reduces its output cell.
//  [480,1920)    cvt f32->bf16 via LDS staging: 32KB/block.
//  [1920,2496)   transpose+cvt w_tp -> WTT
//  [2496,2784)   transpose+cvt conv_w -> WCVT
//  [2784,2824)   cls rows -> GA
//  [2824,2920)   BC[i]  = w_tf[i,:].b_tp + b_tf[i]
//  [2920,3016)   BC2[j] = w_red[j,:].conv_b + b_red[j]
// ---------------------------------------------------------------------------
__global__ __launch_bounds__(256, 2) void prep_kernel(
    const float* __restrict__ x, const float* __restrict__ w_qkv,
    const float* __restrict__ w_tf, const float* __restrict__ w_red,
    const float* __restrict__ conv_w, const float* __restrict__ w_tp,
    const float* __restrict__ b_tp, const float* __restrict__ b_tf,
    const float* __restrict__ conv_b, const float* __restrict__ b_red,
    const float* __restrict__ cls,
    ushort_t* __restrict__ AP, ushort_t* __restrict__ WQ,
    ushort_t* __restrict__ WF, ushort_t* __restrict__ WR,
    ushort_t* __restrict__ WCVT, ushort_t* __restrict__ WTT,
    float* __restrict__ BC, float* __restrict__ BC2,
    float* __restrict__ GA) {
    __shared__ __align__(16) char ldsb[66560];
    float* smem = (float*)ldsb;
    int blk = blockIdx.x, tid = threadIdx.x;
    if (blk < 480) {
        int bt = blk / 3, c = blk % 3;
        int b = bt / 20, t = bt % 20;
        const char* img = (const char*)(x + (size_t)((b * 3 + c) * 20 + t) * 50176);
        int w = tid >> 6, lane = tid & 63;
        int laneoff = lane < 56 ? lane * 16 : 0;   // clamp; slots 896..1023 ignored
        auto stagep = [&](int k, int buf) {
            #pragma unroll
            for (int j2 = 0; j2 < 8; ++j2) {
                int rl = w * 8 + j2;
                int grow = k * 32 + rl;
                load_lds16b(img + (size_t)grow * 896 + laneoff,
                            ldsb + buf * 33280 + rl * 1040);
            }
        };
        int i = tid >> 4, j = tid & 15;
        float acc = 0.f;
        const float* lf = (const float*)ldsb;
        stagep(0, 0);
        for (int k = 0; k < 7; ++k) {
            if (k + 1 < 7) {
                stagep(k + 1, (k + 1) & 1);
                asm volatile("s_waitcnt vmcnt(8)" ::: "memory");
            } else {
                asm volatile("s_waitcnt vmcnt(0)" ::: "memory");
            }
            __builtin_amdgcn_s_barrier();
            __builtin_amdgcn_sched_barrier(0);
            int bb = (k & 1) * 8320;
            #pragma unroll
            for (int rr = 0; rr < 2; ++rr) {
                int rl = i + rr * 16;
                #pragma unroll
                for (int q = 0; q < 14; ++q)
                    acc += lf[bb + rl * 260 + q * 16 + j];
            }
            __builtin_amdgcn_s_barrier();
            __builtin_amdgcn_sched_barrier(0);
        }
        AP[(size_t)bt * 768 + c * 256 + i * 16 + j] = f2bf(acc * (1.f / 196.f));
    } else if (blk < 1920) {
        int blk2 = blk - 480;
        long base = (long)blk2 * 8192;
        const float* s; ushort_t* d; long i0;
        if (blk2 < 864)       { s = w_qkv; d = WQ; i0 = base; }
        else if (blk2 < 1152) { s = w_tf;  d = WF; i0 = base - 7077888; }
        else                  { s = w_red; d = WR; i0 = base - 9437184; }
        int w = tid >> 6, lane = tid & 63;
        #pragma unroll
        for (int j2 = 0; j2 < 8; ++j2) {
            int slot = w * 8 + j2;
            load_lds16b((const char*)(s + i0 + slot * 256) + lane * 16,
                        ldsb + slot * 1024);
        }
        asm volatile("s_waitcnt vmcnt(0)" ::: "memory");
        __builtin_amdgcn_s_barrier();
        __builtin_amdgcn_sched_barrier(0);
        const f32x4* lf4 = (const f32x4*)ldsb;
        #pragma unroll
        for (int r = 0; r < 8; ++r) {
            f32x4 v = lf4[r * 256 + tid];
            ushort4 o;
            o.x = f2bf(v[0]); o.y = f2bf(v[1]); o.z = f2bf(v[2]); o.w = f2bf(v[3]);
            *(ushort4*)(d + i0 + r * 1024 + tid * 4) = o;
        }
    } else if (blk < 2496) {
        int tb = blk - 1920;
        int bi = tb / 24, bj = tb % 24;
        int r0 = (tid >> 4) << 2;
        int c0 = (tid & 15) << 2;
        #pragma unroll
        for (int rr = 0; rr < 4; ++rr) {
            f32x4 v = *(const f32x4*)(w_tp + (size_t)(bi * 64 + r0 + rr) * 1536 + bj * 64 + c0);
            smem[(r0 + rr) * 68 + c0 + 0] = v[0];
            smem[(r0 + rr) * 68 + c0 + 1] = v[1];
            smem[(r0 + rr) * 68 + c0 + 2] = v[2];
            smem[(r0 + rr) * 68 + c0 + 3] = v[3];
        }
        __syncthreads();
        #pragma unroll
        for (int rr = 0; rr < 4; ++rr) {
            int jj = r0 + rr;
            ushort4 o;
            o.x = f2bf(smem[(c0 + 0) * 68 + jj]);
            o.y = f2bf(smem[(c0 + 1) * 68 + jj]);
            o.z = f2bf(smem[(c0 + 2) * 68 + jj]);
            o.w = f2bf(smem[(c0 + 3) * 68 + jj]);
            *(ushort4*)(WTT + (size_t)(bj * 64 + jj) * 1536 + bi * 64 + c0) = o;
        }
    } else if (blk < 2784) {
        int tb = blk - 2496;
        int bi = tb / 12, bj = tb % 12;
        int r0 = (tid >> 4) << 2;
        int c0 = (tid & 15) << 2;
        #pragma unroll
        for (int rr = 0; rr < 4; ++rr) {
            f32x4 v = *(const f32x4*)(conv_w + (size_t)(bi * 64 + r0 + rr) * 768 + bj * 64 + c0);
            smem[(r0 + rr) * 68 + c0 + 0] = v[0];
            smem[(r0 + rr) * 68 + c0 + 1] = v[1];
            smem[(r0 + rr) * 68 + c0 + 2] = v[2];
            smem[(r0 + rr) * 68 + c0 + 3] = v[3];
        }
        __syncthreads();
        #pragma unroll
        for (int rr = 0; rr < 4; ++rr) {
            int jj = r0 + rr;
            ushort4 o;
            o.x = f2bf(smem[(c0 + 0) * 68 + jj]);
            o.y = f2bf(smem[(c0 + 1) * 68 + jj]);
            o.z = f2bf(smem[(c0 + 2) * 68 + jj]);
            o.w = f2bf(smem[(c0 + 3) * 68 + jj]);
            *(ushort4*)(WCVT + (size_t)(bj * 64 + jj) * 1536 + bi * 64 + c0) = o;
        }
    } else if (blk < 2824) {
        int cblk = blk - 2784;
        int b = cblk / 5, n = cblk % 5;
        size_t row = (size_t)(b * 25 + n * 5) * 1536;
        #pragma unroll
        for (int j = 0; j < 6; ++j) {
            int d = tid + j * 256;
            GA[row + d] = cls[n * 1536 + d];
        }
    } else if (blk < 2920) {
        int bb = blk - 2824;
        int row = bb * 16 + (tid >> 4);
        int sub = tid & 15;
        float acc = 0.f;
        for (int j = 0; j < 96; ++j) {
            int k = sub + j * 16;
            acc += w_tf[(size_t)row * 1536 + k] * b_tp[k];
        }
        acc += __shfl_xor(acc, 1); acc += __shfl_xor(acc, 2);
        acc += __shfl_xor(acc, 4); acc += __shfl_xor(acc, 8);
        if (sub == 0) BC[row] = acc + b_tf[row];
    } else {
        int bb = blk - 2920;
        int row = bb * 16 + (tid >> 4);
        int sub = tid & 15;
        float acc = 0.f;
        for (int j = 0; j < 48; ++j) {
            int n0 = sub + j * 16;
            acc += w_red[(size_t)row * 1536 + n0] * conv_b[n0];
            acc += w_red[(size_t)row * 1536 + n0 + 768] * conv_b[n0 + 768];
        }
        acc += __shfl_xor(acc, 1); acc += __shfl_xor(acc, 2);
        acc += __shfl_xor(acc, 4); acc += __shfl_xor(acc, 8);
        if (sub == 0) BC2[row] = acc + b_red[row];
    }
}

// ---------------------------------------------------------------------------
// 128x128-tile 4-wave GEMM tile (r16, verified)
// ---------------------------------------------------------------------------
template <bool OUT_BF16>
__device__ __forceinline__ void gemm128_tile(
    char* lds, const ushort_t* __restrict__ A, const ushort_t* __restrict__ B,
    void* __restrict__ Cv, int M, int N, int K, int KS, int tn, int tm) {
    const int tid = threadIdx.x;
    const int lane = tid & 63;
    const int w = tid >> 6;
    const int wr = w >> 1, wc = w & 1;

    f32x4 acc[4][4];
    #pragma unroll
    for (int m = 0; m < 4; ++m)
        #pragma unroll
        for (int n = 0; n < 4; ++n)
            acc[m][n] = (f32x4){0.f, 0.f, 0.f, 0.f};

    const int nK = K >> 6;
    const int rbase = lane >> 3, cc = lane & 7;

    auto stage = [&](int k0, int buf) {
        char* lA = lds + buf * 32768;
        char* lB = lA + 16384;
        #pragma unroll
        for (int j = 0; j < 4; ++j) {
            int row = w * 32 + j * 8 + rbase;
            int cf = cc ^ (row & 7);
            int ga = tm * 128 + row; if (ga > M - 1) ga = M - 1;
            load_lds16b(A + (size_t)ga * KS + (k0 + cf * 8),
                        lA + (w * 32 + j * 8) * 128);
        }
        #pragma unroll
        for (int j = 0; j < 4; ++j) {
            int row = w * 32 + j * 8 + rbase;
            int cf = cc ^ (row & 7);
            load_lds16b(B + (size_t)(tn * 128 + row) * KS + (k0 + cf * 8),
                        lB + (w * 32 + j * 8) * 128);
        }
    };

    stage(0, 0);
    asm volatile("s_waitcnt vmcnt(0)" ::: "memory");
    __builtin_amdgcn_s_barrier();
    __builtin_amdgcn_sched_barrier(0);
    for (int t = 0; t < nK; ++t) {
        int cur = t & 1;
        if (t + 1 < nK) stage((t + 1) << 6, cur ^ 1);
        __builtin_amdgcn_sched_barrier(0);
        const char* lA = lds + cur * 32768;
        const char* lB = lA + 16384;
        #pragma unroll
        for (int ks = 0; ks < 2; ++ks) {
            short8 av[4], bv[4];
            const int rlo = lane & 15;
            const int chi = ks * 4 + (lane >> 4);
            #pragma unroll
            for (int m = 0; m < 4; ++m) {
                int r = wr * 64 + m * 16 + rlo;
                av[m] = *(const short8*)(lA + r * 128 + ((chi ^ (r & 7)) << 4));
            }
            #pragma unroll
            for (int n = 0; n < 4; ++n) {
                int r = wc * 64 + n * 16 + rlo;
                bv[n] = *(const short8*)(lB + r * 128 + ((chi ^ (r & 7)) << 4));
            }
            #pragma unroll
            for (int m = 0; m < 4; ++m)
                #pragma unroll
                for (int n = 0; n < 4; ++n)
                    acc[m][n] = __builtin_amdgcn_mfma_f32_16x16x32_bf16(
                        av[m], bv[n], acc[m][n], 0, 0, 0);
        }
        asm volatile("s_waitcnt vmcnt(0)" ::: "memory");
        __builtin_amdgcn_s_barrier();
        __builtin_amdgcn_sched_barrier(0);
    }

    const int c_l = lane & 15, r_q = (lane >> 4) * 4;
    #pragma unroll
    for (int m = 0; m < 4; ++m) {
        #pragma unroll
        for (int reg = 0; reg < 4; ++reg) {
            int r_ = tm * 128 + wr * 64 + m * 16 + r_q + reg;
            if (r_ < M) {
                #pragma unroll
                for (int n = 0; n < 4; ++n) {
                    int cc_ = tn * 128 + wc * 64 + n * 16 + c_l;
                    float v = acc[m][n][reg];
                    if (OUT_BF16) ((ushort_t*)Cv)[(size_t)r_ * N + cc_] = f2bf(v);
                    else          ((float*)Cv)[(size_t)r_ * N + cc_] = v;
                }
            }
        }
    }
}

// Wc (144 tiles) + WRC (72 tiles), one 128-tile launch
__global__ __launch_bounds__(256) void wcf_kernel(
    const ushort_t* __restrict__ WF, const ushort_t* __restrict__ WTT,
    const ushort_t* __restrict__ WR, const ushort_t* __restrict__ WCVT,
    ushort_t* __restrict__ WC, ushort_t* __restrict__ WRC) {
    __shared__ __align__(16) char lds[65536];
    int task = blockIdx.x;
    if (task < 144)
        gemm128_tile<true>(lds, WF, WTT, WC, 1536, 1536, 1536, 1536,
                           task % 12, task / 12);
    else {
        int t2 = task - 144;
        gemm128_tile<true>(lds, WR, WCVT, WRC, 1536, 768, 1536, 1536,
                           t2 % 6, t2 / 6);
    }
}

// ---------------------------------------------------------------------------
// single-wave GEMM tile (round-13, unchanged)
// ---------------------------------------------------------------------------
template <int MT, bool OUT_BF16, bool HAS_BIAS, bool HAS_RES, bool CLS_SWAP, bool BUILD_G>
__device__ __forceinline__ void gemm_tile(
    char* lds, int lane, int tn, int tm,
    const ushort_t* __restrict__ A, const ushort_t* __restrict__ B,
    void* __restrict__ Cv, const float* __restrict__ bias,
    const float* __restrict__ res, int M, int N, int K, int KS,
    float* __restrict__ g_out, const float* __restrict__ temb,
    const float* __restrict__ ts, const float* __restrict__ w_num,
    const float* __restrict__ b_num) {
    constexpr int BUFB = MT * 2048 + 8192;

    f32x4 acc[MT][4];
    #pragma unroll
    for (int m = 0; m < MT; ++m)
        #pragma unroll
        for (int n = 0; n < 4; ++n)
            acc[m][n] = (f32x4){0.f, 0.f, 0.f, 0.f};

    const int nK = K >> 6;
    const int rbase = lane >> 3, cc = lane & 7;

    auto stage = [&](int k0, int buf) {
        char* lA = lds + buf * BUFB;
        char* lB = lA + MT * 2048;
        #pragma unroll
        for (int j = 0; j < MT * 2; ++j) {
            int row = j * 8 + rbase;
            int cf = cc ^ (row & 7);
            int ga = tm * (MT * 16) + row; if (ga > M - 1) ga = M - 1;
            load_lds16b(A + (size_t)ga * KS + (k0 + cf * 8), lA + j * 1024);
        }
        #pragma unroll
        for (int j = 0; j < 8; ++j) {
            int row = j * 8 + rbase;
            int cf = cc ^ (row & 7);
            load_lds16b(B + (size_t)(tn * 64 + row) * KS + (k0 + cf * 8), lB + j * 1024);
        }
    };

    stage(0, 0);
    for (int t = 0; t < nK; ++t) {
        int cur = t & 1;
        if (t + 1 < nK) {
            stage((t + 1) << 6, cur ^ 1);
            if constexpr (MT == 2) asm volatile("s_waitcnt vmcnt(12)" ::: "memory");
            else                   asm volatile("s_waitcnt vmcnt(16)" ::: "memory");
        } else {
            asm volatile("s_waitcnt vmcnt(0)" ::: "memory");
        }
        __builtin_amdgcn_sched_barrier(0);
        const char* lA = lds + cur * BUFB;
        const char* lB = lA + MT * 2048;
        #pragma unroll
        for (int ks = 0; ks < 2; ++ks) {
            short8 av[MT], bv[4];
            const int rlo = lane & 15;
            const int chi = ks * 4 + (lane >> 4);
            #pragma unroll
            for (int m = 0; m < MT; ++m) {
                int r = m * 16 + rlo;
                av[m] = *(const short8*)(lA + r * 128 + ((chi ^ (r & 7)) << 4));
            }
            #pragma unroll
            for (int n = 0; n < 4; ++n) {
                int r = n * 16 + rlo;
                bv[n] = *(const short8*)(lB + r * 128 + ((chi ^ (r & 7)) << 4));
            }
            #pragma unroll
            for (int m = 0; m < MT; ++m)
                #pragma unroll
                for (int n = 0; n < 4; ++n)
                    acc[m][n] = __builtin_amdgcn_mfma_f32_16x16x32_bf16(
                        av[m], bv[n], acc[m][n], 0, 0, 0);
        }
    }

    const int c_l = lane & 15, r_q = (lane >> 4) * 4;
    #pragma unroll
    for (int m = 0; m < MT; ++m) {
        #pragma unroll
        for (int reg = 0; reg < 4; ++reg) {
            int r_ = tm * (MT * 16) + m * 16 + r_q + reg;
            if (r_ < M) {
                int r2 = r_;
                if (CLS_SWAP) {
                    int bb = r_ / 25, rem = r_ % 25;
                    if (rem % 5 == 0) r2 = bb * 25 + ((rem / 5 + 1) % 5) * 5;
                }
                #pragma unroll
                for (int n = 0; n < 4; ++n) {
                    int cc_ = tn * 64 + n * 16 + c_l;
                    float v = acc[m][n][reg];
                    if (HAS_BIAS) v += bias[cc_];
                    if (HAS_RES) v += res[(size_t)r_ * N + cc_];
                    if (OUT_BF16) ((ushort_t*)Cv)[(size_t)r2 * N + cc_] = f2bf(v);
                    else          ((float*)Cv)[(size_t)r2 * N + cc_] = v;
                    if (BUILD_G) {
                        int b = r_ / 20, t = r_ % 20;
                        float gval = v + temb[t * 1536 + cc_] +
                                     ts[b] * w_num[cc_] + b_num[cc_];
                        g_out[(size_t)(b * 25 + (t / 4) * 5 + (t % 4) + 1) * 1536 + cc_] = gval;
                    }
                }
            }
        }
    }
}

// xr = AP @ WRC^T + BC2 (f32) + BUILD_G
__global__ __launch_bounds__(64) void xr_kernel(
    const ushort_t* __restrict__ AP, const ushort_t* __restrict__ WRC,
    float* __restrict__ XR, const float* __restrict__ BC2,
    float* __restrict__ GA, const float* __restrict__ temb,
    const float* __restrict__ ts, const float* __restrict__ w_num,
    const float* __restrict__ b_num) {
    __shared__ __align__(16) char lds[24576];
    gemm_tile<2, false, true, false, false, true>(
        lds, threadIdx.x, blockIdx.x, blockIdx.y, AP, WRC, XR, BC2, nullptr,
        160, 1536, 768, 768, GA, temb, ts, w_num, b_num);
}

// qkv split-K x2 (f32 halves)
__global__ __launch_bounds__(64) void qkv_kernel(
    const ushort_t* __restrict__ HN, const ushort_t* __restrict__ WQ,
    float* __restrict__ C0, float* __restrict__ C1) {
    __shared__ __align__(16) char lds[32768];
    int tn = blockIdx.x, tmh = blockIdx.y;
    int half = tmh >> 2, tm = tmh & 3;
    gemm_tile<4, false, false, false, false, false>(
        lds, threadIdx.x, tn, tm, HN + half * 768, WQ + half * 768,
        half ? C1 : C0, nullptr, nullptr, 200, 4608, 768, 1536,
        nullptr, nullptr, nullptr, nullptr, nullptr);
}

// proj: gdst = OBF @ WC^T + BC + gsrc, cls-swap (f32 out)
__global__ __launch_bounds__(64) void proj_kernel(
    const ushort_t* __restrict__ OBF, const ushort_t* __restrict__ WC,
    float* __restrict__ gdst, const float* __restrict__ BC,
    const float* __restrict__ gsrc) {
    __shared__ __align__(16) char lds[24576];
    gemm_tile<2, false, true, true, true, false>(
        lds, threadIdx.x, blockIdx.x, blockIdx.y, OBF, WC, gdst, BC, gsrc,
        200, 1536, 1536, 1536, nullptr, nullptr, nullptr, nullptr, nullptr);
}

// ---------------------------------------------------------------------------
// LayerNorm over D=1536 -> bf16 (unchanged)
// ---------------------------------------------------------------------------
__global__ __launch_bounds__(256) void ln_kernel(
    const float* __restrict__ g, const float* __restrict__ gamma,
    const float* __restrict__ beta, ushort_t* __restrict__ hn) {
    int r = blockIdx.x, tid = threadIdx.x;
    const float* x = g + (size_t)r * 1536;
    float v[6], s = 0.f, s2 = 0.f;
    #pragma unroll
    for (int j = 0; j < 6; ++j) {
        v[j] = x[tid + j * 256];
        s += v[j]; s2 += v[j] * v[j];
    }
    #pragma unroll
    for (int m = 1; m < 64; m <<= 1) { s += __shfl_xor(s, m); s2 += __shfl_xor(s2, m); }
    __shared__ float red[8];
    int wid = tid >> 6;
    if ((tid & 63) == 0) { red[wid] = s; red[4 + wid] = s2; }
    __syncthreads();
    s  = red[0] + red[1] + red[2] + red[3];
    s2 = red[4] + red[5] + red[6] + red[7];
    float mean = s * (1.0f / 1536.0f);
    float var  = s2 * (1.0f / 1536.0f) - mean * mean;
    float rstd = rsqrtf(var + 1e-5f);
    #pragma unroll
    for (int j = 0; j < 6; ++j) {
        int d = tid + j * 256;
        float y = (v[j] - mean) * rstd * gamma[d] + beta[d];
        hn[(size_t)r * 1536 + d] = f2bf(y);
    }
}

// ---------------------------------------------------------------------------
// Attention: sums split-K halves (unchanged)
// ---------------------------------------------------------------------------
__global__ __launch_bounds__(64) void attn_kernel(
    const float* __restrict__ qA, const float* __restrict__ qB,
    ushort_t* __restrict__ o) {
    int gid = blockIdx.x;
    int h = gid % 12, gg = gid / 12;
    int l = threadIdx.x;
    size_t off = (size_t)gg * 5 * 4608 + h * 128 + 2 * l;
    const float* b0 = qA + off;
    const float* b1 = qB + off;
    float q[5][2], k[5][2], v[5][2];
    #pragma unroll
    for (int tt = 0; tt < 5; ++tt) {
        float2 q0 = *(const float2*)(b0 + tt * 4608);
        float2 q1 = *(const float2*)(b1 + tt * 4608);
        float2 k0 = *(const float2*)(b0 + tt * 4608 + 1536);
        float2 k1 = *(const float2*)(b1 + tt * 4608 + 1536);
        float2 v0 = *(const float2*)(b0 + tt * 4608 + 3072);
        float2 v1 = *(const float2*)(b1 + tt * 4608 + 3072);
        q[tt][0] = q0.x + q1.x; q[tt][1] = q0.y + q1.y;
        k[tt][0] = k0.x + k1.x; k[tt][1] = k0.y + k1.y;
        v[tt][0] = v0.x + v1.x; v[tt][1] = v0.y + v1.y;
    }
    float sc[5][5];
    #pragma unroll
    for (int i = 0; i < 5; ++i)
        #pragma unroll
        for (int j = 0; j < 5; ++j)
            sc[i][j] = q[i][0] * k[j][0] + q[i][1] * k[j][1];
    #pragma unroll
    for (int m = 1; m < 64; m <<= 1)
        #pragma unroll
        for (int i = 0; i < 5; ++i)
            #pragma unroll
            for (int j = 0; j < 5; ++j)
                sc[i][j] += __shfl_xor(sc[i][j], m);
    const float scale = 0.08838834764831845f;
    float a_[5][5];
    #pragma unroll
    for (int i = 0; i < 5; ++i) {
        float mx = -1e30f;
        #pragma unroll
        for (int j = 0; j < 5; ++j) mx = fmaxf(mx, sc[i][j]);
        float sum = 0.f;
        #pragma unroll
        for (int j = 0; j < 5; ++j) { a_[i][j] = __expf((sc[i][j] - mx) * scale); sum += a_[i][j]; }
        float inv = 1.0f / sum;
        #pragma unroll
        for (int j = 0; j < 5; ++j) a_[i][j] *= inv;
    }
    #pragma unroll
    for (int i = 0; i < 5; ++i) {
        float o0 = 0.f, o1 = 0.f;
        #pragma unroll
        for (int j = 0; j < 5; ++j) { o0 += a_[i][j] * v[j][0]; o1 += a_[i][j] * v[j][1]; }
        ushort2 w; w.x = f2bf(o0); w.y = f2bf(o1);
        *(ushort2*)(o + (size_t)(gg * 5 + i) * 1536 + h * 128 + 2 * l) = w;
    }
}

// ---------------------------------------------------------------------------
// Head (unchanged)
// ---------------------------------------------------------------------------
__global__ __launch_bounds__(64) void head_kernel(
    const float* __restrict__ gfin, const float* __restrict__ xr,
    const float* __restrict__ w_head, const float* __restrict__ b_head,
    float* __restrict__ out) {
    int b = blockIdx.x, l = threadIdx.x;
    const float* gv = gfin + (size_t)(b * 25 + 24) * 1536;
    const float* xv = xr + (size_t)(b * 20 + 19) * 1536;
    float acc[7] = {0, 0, 0, 0, 0, 0, 0};
    for (int d = l; d < 1536; d += 64) {
        float xval = gv[d] + xv[d];
        #pragma unroll
        for (int c = 0; c < 7; ++c) acc[c] += xval * w_head[c * 1536 + d];
    }
    #pragma unroll
    for (int c = 0; c < 7; ++c)
        #pragma unroll
        for (int m = 1; m < 64; m <<= 1) acc[c] += __shfl_xor(acc[c], m);
    if (l == 0) {
        #pragma unroll
        for (int c = 0; c < 7; ++c) out[b * 7 + c] = acc[c] + b_head[c];
    }
}

// ---------------------------------------------------------------------------
// Workspace layout (bytes)
// ---------------------------------------------------------------------------
#define OFF_WQ    0u          // 14155776
#define OFF_WF    14155776u   // 4718592
#define OFF_WR    18874368u   // 4718592
#define OFF_WCVT  23592960u   // 2359296
#define OFF_WTT   25952256u   // 4718592
#define OFF_WC    30670848u   // 4718592
#define OFF_WRC   35389440u   // 2359296
#define OFF_BC    37748736u   // 6144
#define OFF_BC2   37754880u   // 6144
#define OFF_AP    37761024u   // 245760
#define OFF_XR    38006784u   // 983040
#define OFF_GA    38989824u   // 1228800
#define OFF_GB    40218624u   // 1228800
#define OFF_HN    41447424u   // 614400
#define OFF_QKV0  42061824u   // 3686400
#define OFF_QKV1  45748224u   // 3686400
#define OFF_OBF   49434624u   // 614400

extern "C" void kernel_launch(void* const* d_in, const int* in_sizes, int n_in,
                              void* d_out, int out_size, void* d_ws, size_t ws_size,
                              hipStream_t stream) {
    const float* x      = (const float*)d_in[0];
    const float* ts     = (const float*)d_in[1];
    const float* conv_w = (const float*)d_in[2];
    const float* conv_b = (const float*)d_in[3];
    const float* w_red  = (const float*)d_in[4];
    const float* b_red  = (const float*)d_in[5];
    const float* w_num  = (const float*)d_in[6];
    const float* b_num  = (const float*)d_in[7];
    const float* temb   = (const float*)d_in[8];
    const float* cls    = (const float*)d_in[9];
    const float* ln_g   = (const float*)d_in[10];
    const float* ln_b   = (const float*)d_in[11];
    const float* w_qkv  = (const float*)d_in[12];
    const float* w_tp   = (const float*)d_in[13];
    const float* b_tp   = (const float*)d_in[14];
    const float* w_tf   = (const float*)d_in[15];
    const float* b_tf   = (const float*)d_in[16];
    const float* w_head = (const float*)d_in[17];
    const float* b_head = (const float*)d_in[18];

    char* ws = (char*)d_ws;
    ushort_t* WQ   = (ushort_t*)(ws + OFF_WQ);
    ushort_t* WF   = (ushort_t*)(ws + OFF_WF);
    ushort_t* WR   = (ushort_t*)(ws + OFF_WR);
    ushort_t* WCVT = (ushort_t*)(ws + OFF_WCVT);
    ushort_t* WTT  = (ushort_t*)(ws + OFF_WTT);
    ushort_t* WC   = (ushort_t*)(ws + OFF_WC);
    ushort_t* WRC  = (ushort_t*)(ws + OFF_WRC);
    float*    BC   = (float*)(ws + OFF_BC);
    float*    BC2  = (float*)(ws + OFF_BC2);
    ushort_t* AP   = (ushort_t*)(ws + OFF_AP);
    float*    XR   = (float*)(ws + OFF_XR);
    float*    GA   = (float*)(ws + OFF_GA);
    float*    GB   = (float*)(ws + OFF_GB);
    ushort_t* HN   = (ushort_t*)(ws + OFF_HN);
    float*    QKV0 = (float*)(ws + OFF_QKV0);
    float*    QKV1 = (float*)(ws + OFF_QKV1);
    ushort_t* OBF  = (ushort_t*)(ws + OFF_OBF);

    // 1) prep: pool + weight prep via global_load_lds staging
    prep_kernel<<<3016, 256, 0, stream>>>(x, w_qkv, w_tf, w_red, conv_w, w_tp,
                                          b_tp, b_tf, conv_b, b_red, cls,
                                          AP, WQ, WF, WR, WCVT, WTT, BC, BC2, GA);
    // 2) Wc + WRC (one 128-tile launch)
    wcf_kernel<<<216, 256, 0, stream>>>(WF, WTT, WR, WCVT, WC, WRC);
    // 3) xr = AP @ WRC^T + BC2 (f32) + build g rows
    xr_kernel<<<dim3(24, 5), 64, 0, stream>>>(AP, WRC, XR, BC2, GA,
                                              temb, ts, w_num, b_num);
    // 4) loop
    float* gsrc = GA;
    float* gdst = GB;
    for (int it = 0; it < 4; ++it) {
        ln_kernel<<<200, 256, 0, stream>>>(gsrc, ln_g, ln_b, HN);
        qkv_kernel<<<dim3(72, 8), 64, 0, stream>>>(HN, WQ, QKV0, QKV1);
        attn_kernel<<<480, 64, 0, stream>>>(QKV0, QKV1, OBF);
        proj_kernel<<<dim3(24, 7), 64, 0, stream>>>(OBF, WC, gdst, BC, gsrc);
        float* tmp = gsrc; gsrc = gdst; gdst = tmp;
    }
    // 5) head
    head_kernel<<<8, 64, 0, stream>>>(gsrc, XR, w_head, b_head, (float*)d_out);
}